// Round 14
// baseline (436.102 us; speedup 1.0000x reference)
//
#include <hip/hip_runtime.h>
#include <hip/hip_bf16.h>

typedef __attribute__((ext_vector_type(8))) short short8;
typedef __attribute__((ext_vector_type(4))) float f32x4;

__device__ __forceinline__ short f2bf(float f) {
  unsigned u = __float_as_uint(f);
  u += 0x7fffu + ((u >> 16) & 1u);   // RNE
  return (short)(u >> 16);
}

__device__ __forceinline__ void gload16(const short* g, short* l) {
  __builtin_amdgcn_global_load_lds(
      (const __attribute__((address_space(1))) unsigned int*)g,
      (__attribute__((address_space(3))) unsigned int*)l, 16, 0, 0);
}

// ---------------- weight repack segment table ----------------------------------------
struct WSeg { const float* src; short* dst; int Ci; int S; int elems; };
struct WPrep { WSeg seg[20]; };

// ---------------- fused prep kernel ---------------------------------------------------
struct PrepPack {
  const float* f0; short* f0dst; const float* l2w;
  const float* f1; short* f1dst;
  WPrep wp; int wtotal;
  int nF0, nF1;
};

__global__ __launch_bounds__(256) void prep_kernel(PrepPack pp) {
  __shared__ float red[8][32];
  __shared__ float sscale[32];
  __shared__ float tile[32][33];
  int id = blockIdx.x;
  if (id < pp.nF0) {
    // ---- feat0: L2Norm + transpose (H=W=38, Wp=40, nstride=1600, hh=1, C=512) ----
    constexpr int C = 512, H = 38, W = 38, Wp = 40, nstride = 1600, hh = 1;
    int bx = id % 46, n = id / 46;
    int P = H * W;
    int p0 = bx * 32;
    int pl = threadIdx.x & 31, cg = threadIdx.x >> 5;
    const float* s = pp.f0 + (size_t)n * C * P;
    float ss = 0.f;
    int p = p0 + pl;
    if (p < P) {
      for (int k = 0; k < 64; ++k) {
        float v = s[(size_t)(cg * 64 + k) * P + p];
        ss += v * v;
      }
    }
    red[cg][pl] = ss;
    __syncthreads();
    if (threadIdx.x < 32) {
      float tot = 0.f;
      #pragma unroll
      for (int g = 0; g < 8; ++g) tot += red[g][threadIdx.x];
      sscale[threadIdx.x] = 1.0f / (sqrtf(tot) + 1e-10f);
    }
    __syncthreads();
    for (int ct = 0; ct < 16; ++ct) {
      int c0 = ct * 32;
      __syncthreads();
      #pragma unroll
      for (int i = 0; i < 4; ++i) {
        int cl = cg + i * 8;
        tile[cl][pl] = (p < P) ? s[(size_t)(c0 + cl) * P + p] : 0.f;
      }
      __syncthreads();
      #pragma unroll
      for (int i = 0; i < 4; ++i) {
        int pll = cg + i * 8;
        int pp2 = p0 + pll;
        if (pp2 >= P) continue;
        int c = c0 + pl;
        float v = tile[pl][pll] * pp.l2w[c] * sscale[pll];
        int y = pp2 / W, x = pp2 - y * W;
        pp.f0dst[((size_t)n * nstride + (y + hh) * Wp + (x + hh)) * C + c] = f2bf(v);
      }
    }
    return;
  }
  id -= pp.nF0;
  if (id < pp.nF1) {
    // ---- feat1: transpose (C=1024, H=W=19, Wp=21, nstride=441, hh=1) ----
    constexpr int C = 1024, H = 19, W = 19, Wp = 21, nstride = 441, hh = 1;
    int bx = id % 12, byc = (id / 12) % 32, n = id / (12 * 32);
    int P = H * W;
    int p0 = bx * 32, c0 = byc * 32;
    int tp = threadIdx.x & 31, tr = threadIdx.x >> 5;
    const float* s = pp.f1 + (size_t)n * C * P;
    #pragma unroll
    for (int i = 0; i < 4; ++i) {
      int cl = tr + i * 8;
      int p = p0 + tp;
      tile[cl][tp] = (p < P) ? s[(size_t)(c0 + cl) * P + p] : 0.f;
    }
    __syncthreads();
    #pragma unroll
    for (int i = 0; i < 4; ++i) {
      int pl = tr + i * 8;
      int p = p0 + pl;
      if (p >= P) continue;
      int c = c0 + tp;
      float v = tile[tp][pl];
      int y = p / W, x = p - y * W;
      pp.f1dst[((size_t)n * nstride + (y + hh) * Wp + (x + hh)) * C + c] = f2bf(v);
    }
    return;
  }
  id -= pp.nF1;
  // ---- weight repack ----
  int i = id * 256 + threadIdx.x;
  if (i >= pp.wtotal) return;
  int local = i;
  int si = 0;
  while (local >= pp.wp.seg[si].elems) { local -= pp.wp.seg[si].elems; ++si; }
  WSeg sg = pp.wp.seg[si];
  int ci = local % sg.Ci;
  int q  = local / sg.Ci;
  int s  = q % sg.S;
  int co = q / sg.S;
  float v = sg.src[((size_t)co * sg.Ci + ci) * sg.S + s];
  sg.dst[local] = f2bf(v);
}

// ---------------- conv params --------------------------------------------------------
struct ConvP {
  const short* in;   // bf16 padded NHWC [16][iHp][iWp][Ci]
  const short* w;    // bf16 [Co][S][Ci]
  const float* b1;   // bias (extra) / cls bias (head)
  const float* b2;   // box bias (head)
  short* out_bf;     // extra: padded bf16 NHWC out
  float* out_f;      // head: packed d_out
  int M, Ci, iHp, iWp, Ho, Wo, Co;
  int S, kdim, stride, ioff;
  int oWp, onstride, oh;
  int mbox, row_base;
};

// --- BK/wave-parameterized 2-buffer, 1-barrier/K-step implicit-GEMM core + swizzle ---
// (unchanged from r13 — proven: heads 182us @ MfmaUtil 36.8%, conflicts 0)
template<int BM, int BN, int BK, int WM, int WN, bool HEAD>
__device__ __forceinline__ void conv_core(const ConvP p, int bx, int by) {
  constexpr int NT  = WM * WN * 64;
  constexpr int CPR = BK / 8;
  constexpr int RPP = NT / CPR;
  constexpr int NRA = BM / RPP, NRB = BN / RPP;
  constexpr int AM = BM / WM / 16, AN = BN / WN / 16, KK = BK / 32;
  constexpr int ABUF = BM * BK, BBUF = BN * BK;
  __shared__ short As[2 * ABUF];
  __shared__ short Bs[2 * BBUF];
  const int t = threadIdx.x, lane = t & 63, wave = t >> 6;
  const int HW = p.Ho * p.Wo;
  const int sr = t / CPR;
  const int slot = ((t & (CPR - 1)) ^ (sr & (CPR - 1))) * 8;

  const short* aBase[NRA];
  const short* bBase[NRB];
  #pragma unroll
  for (int i = 0; i < NRA; ++i) {
    int pos = bx * BM + sr + i * RPP; if (pos >= p.M) pos = p.M - 1;
    int n = pos / HW, rem = pos - n * HW;
    int yo = rem / p.Wo, xo = rem - yo * p.Wo;
    aBase[i] = p.in + ((size_t)(n * p.iHp + yo * p.stride + p.ioff) * p.iWp
                      + xo * p.stride + p.ioff) * p.Ci + slot;
  }
  #pragma unroll
  for (int i = 0; i < NRB; ++i) {
    int co = by * BN + sr + i * RPP; if (co >= p.Co) co = p.Co - 1;
    bBase[i] = p.w + (size_t)co * p.S * p.Ci + slot;
  }
  const int cs = p.Ci / BK;
  const int total = p.S * cs;

  auto stage = [&](int buf, int aoff, int boff) {
    #pragma unroll
    for (int i = 0; i < NRA; ++i)
      gload16(aBase[i] + aoff, &As[buf * ABUF + i * (NT * 8) + t * 8]);
    #pragma unroll
    for (int i = 0; i < NRB; ++i)
      gload16(bBase[i] + boff, &Bs[buf * BBUF + i * (NT * 8) + t * 8]);
  };

  int ntap = 0, ncc = 0;
  auto aoff_cur = [&]() -> int {
    if (p.S == 1) return ncc * BK;
    unsigned dy = (unsigned)ntap / 3u;
    int dx = ntap - (int)dy * 3;
    return ((int)dy * p.iWp + dx) * p.Ci + ncc * BK;
  };

  stage(0, aoff_cur(), 0);
  ++ncc; if (ncc == cs) { ncc = 0; ++ntap; }
  __syncthreads();                       // tile 0 landed

  f32x4 acc[AM][AN];
  #pragma unroll
  for (int i = 0; i < AM; ++i)
    #pragma unroll
    for (int j = 0; j < AN; ++j)
      acc[i][j] = (f32x4){0.f, 0.f, 0.f, 0.f};

  const int wr = (wave / WN) * (BM / WM), wc = (wave % WN) * (BN / WN);
  const int lrow = lane & 15, kgrp = lane >> 4;

  int cur = 0;
  for (int ks = 0; ks < total; ++ks) {
    if (ks + 1 < total) {                // issue next tile's loads FIRST (overlap)
      stage(cur ^ 1, aoff_cur(), (ks + 1) * BK);
      ++ncc; if (ncc == cs) { ncc = 0; ++ntap; }
    }
    const short* aRd0 = &As[cur * ABUF];
    const short* bRd0 = &Bs[cur * BBUF];
    short8 a[AM][KK], b[AN][KK];
    #pragma unroll
    for (int i = 0; i < AM; ++i) {
      int r = wr + i * 16 + lrow;
      #pragma unroll
      for (int kk = 0; kk < KK; ++kk) {
        int ch = ((kk << 2) | kgrp) ^ (r & (CPR - 1));
        a[i][kk] = *reinterpret_cast<const short8*>(aRd0 + r * BK + ch * 8);
      }
    }
    #pragma unroll
    for (int j = 0; j < AN; ++j) {
      int r = wc + j * 16 + lrow;
      #pragma unroll
      for (int kk = 0; kk < KK; ++kk) {
        int ch = ((kk << 2) | kgrp) ^ (r & (CPR - 1));
        b[j][kk] = *reinterpret_cast<const short8*>(bRd0 + r * BK + ch * 8);
      }
    }
    #pragma unroll
    for (int kk = 0; kk < KK; ++kk)
      #pragma unroll
      for (int i = 0; i < AM; ++i)
        #pragma unroll
        for (int j = 0; j < AN; ++j)
          acc[i][j] = __builtin_amdgcn_mfma_f32_16x16x32_bf16(a[i][kk], b[j][kk], acc[i][j], 0, 0, 0);
    __syncthreads();                     // drains vmcnt(0): next tile ready; reads done
    cur ^= 1;
  }

  const int mk = p.mbox * 81;
  const int rb_ = (lane >> 4) * 4, cl_ = lane & 15;
  #pragma unroll
  for (int i = 0; i < AM; ++i)
    #pragma unroll
    for (int j = 0; j < AN; ++j)
      #pragma unroll
      for (int q = 0; q < 4; ++q) {
        int po = bx * BM + wr + i * 16 + rb_ + q;
        int co = by * BN + wc + j * 16 + cl_;
        if (po >= p.M || co >= p.Co) continue;
        float v = acc[i][j][q];
        if (!HEAD) {
          int n2 = po / HW, sp = po - n2 * HW;
          int y = sp / p.Wo, x = sp - y * p.Wo;
          float v2 = fmaxf(v + p.b1[co], 0.f);
          p.out_bf[((size_t)n2 * p.onstride + (y + p.oh) * p.oWp + (x + p.oh)) * p.Co + co] = f2bf(v2);
        } else {
          int n2 = po / HW, sp = po - n2 * HW;
          int mi, col; float bias;
          if (co < mk) { mi = co / 81; col = co - mi * 81; bias = p.b1[co]; }
          else { int cbx = co - mk; mi = cbx >> 2; col = 81 + (cbx & 3); bias = p.b2[cbx]; }
          size_t orow = (size_t)n2 * 8732 + p.row_base + (size_t)sp * p.mbox + mi;
          p.out_f[orow * 85 + col] = v + bias;
        }
      }
}

__global__ __launch_bounds__(256) void conv_tile64(ConvP p) {
  conv_core<64, 64, 128, 2, 2, false>(p, blockIdx.x, blockIdx.y);
}

// ---------------- fused extras tail (e2..e7), one block per batch image ---------------
// All intermediates LDS-resident (ping-pong R0/R1, peak 62KB at e3). Per layer: MFMA
// mini-GEMM over (pos x co) fragments split across 8 waves; A from LDS with per-16B
// chunk XOR swizzle (chunk ^= pos&7 — row stride is a multiple of 256B, unswizzled
// would be 16-way bank conflict); B streamed from L2-hot repacked weights; bias+ReLU;
// out written swizzled to LDS (+ global for f3b/f4b/f5b, which heads 3-5 read).
// No inter-block protocol — plain __syncthreads between layers (r11/r12 failure class
// structurally absent). Fragment/lane mapping copied verbatim from conv_core (verified).
template<int iHp, int iWp, int Ci, int ioff, int stride, int kdim, int S,
         int Ho, int Wo, int Co, int oWp, int oh, bool GIN, bool GOUT>
__device__ __forceinline__ void tail_layer(const short* __restrict__ gin,
    const short* lin, const short* __restrict__ w, const float* __restrict__ bias,
    short* lout, short* gout) {
  constexpr int M = Ho * Wo;
  constexpr int FM = (M + 15) / 16;
  constexpr int FC = Co / 16;
  const int lane = threadIdx.x & 63, wave = threadIdx.x >> 6;
  const int l15 = lane & 15, kg = lane >> 4;
  for (int f = wave; f < FM * FC; f += 8) {
    int fm = f % FM, fc = f / FM;
    f32x4 acc = (f32x4){0.f, 0.f, 0.f, 0.f};
    int r = fm * 16 + l15; if (r >= M) r = M - 1;     // clamp (dup compute, write-skipped)
    int yo = r / Wo, xo = r - yo * Wo;
    int co = fc * 16 + l15;
    const short* wrow = w + (size_t)co * S * Ci;
    #pragma unroll
    for (int s = 0; s < S; ++s) {
      int dy = s / kdim, dx = s - dy * kdim;
      int ipos = (yo * stride + dy + ioff) * iWp + (xo * stride + dx + ioff);
      #pragma unroll
      for (int ck = 0; ck < Ci / 32; ++ck) {
        int ci0 = ck * 32 + kg * 8;
        short8 a;
        if (GIN) {
          a = *reinterpret_cast<const short8*>(gin + (size_t)ipos * Ci + ci0);
        } else {
          int sw = (ci0 >> 3) ^ (ipos & 7);
          a = *reinterpret_cast<const short8*>(lin + ipos * Ci + sw * 8);
        }
        short8 b = *reinterpret_cast<const short8*>(wrow + s * Ci + ci0);
        acc = __builtin_amdgcn_mfma_f32_16x16x32_bf16(a, b, acc, 0, 0, 0);
      }
    }
    #pragma unroll
    for (int q = 0; q < 4; ++q) {
      int pos = fm * 16 + kg * 4 + q;                 // C row = (lane>>4)*4+q (m89)
      if (pos >= M) continue;
      int y = pos / Wo, x = pos - y * Wo;
      float v = fmaxf(acc[q] + bias[co], 0.f);
      short bv = f2bf(v);
      int opos = (y + oh) * oWp + (x + oh);
      int swc = (co >> 3) ^ (opos & 7);
      lout[opos * Co + swc * 8 + (co & 7)] = bv;
      if (GOUT) gout[(size_t)opos * Co + co] = bv;
    }
  }
}

__device__ __forceinline__ void zero_lds(short* p, int nshorts) {
  int* q = (int*)p;
  for (int i = threadIdx.x; i < nshorts / 2; i += 512) q[i] = 0;
}

struct TailPack {
  const short* f2b; short* f3b; short* f4b; short* f5b;
  const short* w2; const short* w3; const short* w4; const short* w5;
  const short* w6; const short* w7;
  const float* b2; const float* b3; const float* b4; const float* b5;
  const float* b6; const float* b7;
};

__global__ __launch_bounds__(512) void tail_kernel(TailPack tp) {
  __shared__ short sm[30976];            // R0 18432 + R1 12544 shorts = 61952 B
  short* R0 = sm;
  short* R1 = sm + 18432;
  int n = blockIdx.x;
  // e2: 1x1, f2b(global, 12x12x512 padded) -> xe2 (LDS 12x12x128, h=1)
  zero_lds(R0, 18432); __syncthreads();
  tail_layer<12, 12, 512, 1, 1, 1, 1, 10, 10, 128, 12, 1, true, false>(
      tp.f2b + (size_t)n * 144 * 512, nullptr, tp.w2, tp.b2, R0, nullptr);
  __syncthreads();
  // e3: 3x3 s2 p1 -> f3b (LDS 7x7x256 h=1; + global for head3)
  zero_lds(R1, 12544); __syncthreads();
  tail_layer<12, 12, 128, 0, 2, 3, 9, 5, 5, 256, 7, 1, false, true>(
      nullptr, R0, tp.w3, tp.b3, R1, tp.f3b + (size_t)n * 49 * 256);
  __syncthreads();
  // e4: 1x1 -> xe4 (LDS 5x5x128, no halo)
  zero_lds(R0, 3200); __syncthreads();
  tail_layer<7, 7, 256, 1, 1, 1, 1, 5, 5, 128, 5, 0, false, false>(
      nullptr, R1, tp.w4, tp.b4, R0, nullptr);
  __syncthreads();
  // e5: 3x3 s1 p0 -> f4b (LDS 5x5x256 h=1; + global for head4)
  zero_lds(R1, 6400); __syncthreads();
  tail_layer<5, 5, 128, 0, 1, 3, 9, 3, 3, 256, 5, 1, false, true>(
      nullptr, R0, tp.w5, tp.b5, R1, tp.f4b + (size_t)n * 25 * 256);
  __syncthreads();
  // e6: 1x1 -> xe6 (LDS 3x3x128)
  zero_lds(R0, 1152); __syncthreads();
  tail_layer<5, 5, 256, 1, 1, 1, 1, 3, 3, 128, 3, 0, false, false>(
      nullptr, R1, tp.w6, tp.b6, R0, nullptr);
  __syncthreads();
  // e7: 3x3 s1 p0 -> f5b (LDS 3x3x256 h=1; + global for head5)
  zero_lds(R1, 2304); __syncthreads();
  tail_layer<3, 3, 128, 0, 1, 3, 9, 1, 1, 256, 3, 1, false, true>(
      nullptr, R0, tp.w7, tp.b7, R1, tp.f5b + (size_t)n * 9 * 256);
}

// ------ grouped head kernel: group-preserving, round-robin-balanced XCD mapping ------
struct HeadPack { ConvP L[6]; int g0[6]; int nbyA[6]; int sb[56]; };

__global__ __launch_bounds__(512) void head_grouped(HeadPack h) {
  int p = blockIdx.x, x = p & 7, s = p >> 3;
  if (s >= h.sb[48 + x]) return;         // padding block
  int li = 0;
  #pragma unroll
  for (int i = 1; i < 6; ++i) if (s >= h.sb[i * 8 + x]) li = i;
  int r = s - h.sb[li * 8 + x];
  int nby = h.nbyA[li];
  int k = r / nby, by = r - k * nby;
  int bx = ((x - h.g0[li]) & 7) + 8 * k; // bx of the k-th group of layer li on XCD x
  conv_core<128, 128, 64, 2, 4, true>(h.L[li], bx, by);
}

extern "C" void kernel_launch(void* const* d_in, const int* in_sizes, int n_in,
                              void* d_out, int out_size, void* d_ws, size_t ws_size,
                              hipStream_t stream) {
  const float* feat0 = (const float*)d_in[0];
  const float* feat1 = (const float*)d_in[1];
  const float* l2w   = (const float*)d_in[2];
  const float* ew[8]; const float* eb[8];
  for (int i = 0; i < 8; ++i) { ew[i] = (const float*)d_in[3 + 2 * i]; eb[i] = (const float*)d_in[4 + 2 * i]; }
  const float* cw[6]; const float* cb[6]; const float* bw[6]; const float* bb[6];
  for (int i = 0; i < 6; ++i) {
    cw[i] = (const float*)d_in[19 + 4 * i]; cb[i] = (const float*)d_in[20 + 4 * i];
    bw[i] = (const float*)d_in[21 + 4 * i]; bb[i] = (const float*)d_in[22 + 4 * i];
  }
  float* out = (float*)d_out;
  char* ws = (char*)d_ws;
  size_t off = 0;
  auto alloc = [&](size_t bytes) -> char* {
    char* p = ws + off;
    off = (off + bytes + 255) & ~(size_t)255;
    return p;
  };
  char* featStart = ws + off;
  short* f0b = (short*)alloc((size_t)16 * 40 * 40 * 512 * 2);   // 38x38, h=1
  short* f1b = (short*)alloc((size_t)16 * 21 * 21 * 1024 * 2);  // 19x19, h=1
  short* xe0 = (short*)alloc((size_t)16 * 21 * 21 * 256 * 2);   // 19x19, h=1
  short* f2b = (short*)alloc((size_t)16 * 12 * 12 * 512 * 2);   // 10x10, h=1
  short* f3b = (short*)alloc((size_t)16 * 7 * 7 * 256 * 2);     // 5x5,  h=1
  short* f4b = (short*)alloc((size_t)16 * 5 * 5 * 256 * 2);     // 3x3,  h=1
  short* f5b = (short*)alloc((size_t)16 * 3 * 3 * 256 * 2);     // 1x1,  h=1
  size_t featBytes = (size_t)((ws + off) - featStart);

  static const int eCo[8] = {256, 512, 128, 256, 128, 256, 128, 256};
  static const int eCi[8] = {1024, 256, 512, 128, 256, 128, 256, 128};
  static const int eS[8]  = {1, 9, 1, 9, 1, 9, 1, 9};
  static const int mbox[6] = {4, 6, 6, 6, 4, 4};
  static const int hCi[6] = {512, 1024, 512, 256, 256, 256};

  WPrep wp; int total = 0; int segi = 0;
  short* ewb[8]; short* hwb[6];
  for (int i = 0; i < 8; ++i) {
    int e = eCo[i] * eCi[i] * eS[i];
    ewb[i] = (short*)alloc((size_t)e * 2);
    wp.seg[segi++] = {ew[i], ewb[i], eCi[i], eS[i], e};
    total += e;
  }
  for (int L = 0; L < 6; ++L) {
    int co = mbox[L] * 85;
    int e = co * hCi[L] * 9;
    hwb[L] = (short*)alloc((size_t)e * 2);
    int ecls = mbox[L] * 81 * hCi[L] * 9;
    wp.seg[segi++] = {cw[L], hwb[L], hCi[L], 9, ecls};
    wp.seg[segi++] = {bw[L], hwb[L] + (size_t)mbox[L] * 81 * 9 * hCi[L], hCi[L], 9, e - ecls};
    total += e;
  }

  hipMemsetAsync(featStart, 0, featBytes, stream);

  // fused prep: feat0(L2Norm+transpose) + feat1(transpose) + weight repack, 1 launch
  PrepPack pp;
  pp.f0 = feat0; pp.f0dst = f0b; pp.l2w = l2w;
  pp.f1 = feat1; pp.f1dst = f1b;
  pp.wp = wp; pp.wtotal = total;
  pp.nF0 = 46 * 16;
  pp.nF1 = 12 * 32 * 16;
  int nPrep = pp.nF0 + pp.nF1 + (total + 255) / 256;
  prep_kernel<<<dim3(nPrep), 256, 0, stream>>>(pp);

  auto mkP = [&](const short* in, const short* wbuf, const float* b1, const float* b2,
                 short* outb, float* outf, int Ci, int iHp, int iWp, int Ho, int Wo,
                 int Co, int S, int kd, int st, int ioff, int oWp, int onstride, int oh,
                 int m, int rb) {
    ConvP p{}; p.in = in; p.w = wbuf; p.b1 = b1; p.b2 = b2; p.out_bf = outb; p.out_f = outf;
    p.M = 16 * Ho * Wo; p.Ci = Ci; p.iHp = iHp; p.iWp = iWp; p.Ho = Ho; p.Wo = Wo; p.Co = Co;
    p.S = S; p.kdim = kd; p.stride = st; p.ioff = ioff;
    p.oWp = oWp; p.onstride = onstride; p.oh = oh; p.mbox = m; p.row_base = rb;
    return p;
  };
  auto run64 = [&](ConvP p) {
    conv_tile64<<<dim3((p.M + 63) / 64, (p.Co + 63) / 64), 256, 0, stream>>>(p);
  };

  // e0, e1 keep the proven parallel GEMM kernels (real grids)
  run64(mkP(f1b, ewb[0], eb[0], nullptr, xe0, nullptr, 1024, 21, 21, 19, 19, 256, 1, 1, 1, 1, 21, 441, 1, 0, 0));
  run64(mkP(xe0, ewb[1], eb[1], nullptr, f2b, nullptr,  256, 21, 21, 10, 10, 512, 9, 3, 2, 0, 12, 144, 1, 0, 0));

  // e2..e7 fused: one block per batch image, LDS-resident chain
  TailPack tp;
  tp.f2b = f2b; tp.f3b = f3b; tp.f4b = f4b; tp.f5b = f5b;
  tp.w2 = ewb[2]; tp.w3 = ewb[3]; tp.w4 = ewb[4]; tp.w5 = ewb[5]; tp.w6 = ewb[6]; tp.w7 = ewb[7];
  tp.b2 = eb[2]; tp.b3 = eb[3]; tp.b4 = eb[4]; tp.b5 = eb[5]; tp.b6 = eb[6]; tp.b7 = eb[7];
  tail_kernel<<<dim3(16), 512, 0, stream>>>(tp);

  // all 6 heads in ONE launch (long-K head1 first in group enumeration)
  HeadPack h;
  h.L[0] = mkP(f1b, hwb[1], cb[1], bb[1], nullptr, out, 1024, 21, 21, 19, 19, 6 * 85, 9, 3, 1, 0, 0, 0, 0, 6, 5776);
  h.L[1] = mkP(f0b, hwb[0], cb[0], bb[0], nullptr, out,  512, 40, 40, 38, 38, 4 * 85, 9, 3, 1, 0, 0, 0, 0, 4, 0);
  h.L[2] = mkP(f2b, hwb[2], cb[2], bb[2], nullptr, out,  512, 12, 12, 10, 10, 6 * 85, 9, 3, 1, 0, 0, 0, 0, 6, 7942);
  h.L[3] = mkP(f3b, hwb[3], cb[3], bb[3], nullptr, out,  256,  7,  7,  5,  5, 6 * 85, 9, 3, 1, 0, 0, 0, 0, 6, 8542);
  h.L[4] = mkP(f4b, hwb[4], cb[4], bb[4], nullptr, out,  256,  5,  5,  3,  3, 4 * 85, 9, 3, 1, 0, 0, 0, 0, 4, 8692);
  h.L[5] = mkP(f5b, hwb[5], cb[5], bb[5], nullptr, out,  256,  3,  3,  1,  1, 4 * 85, 9, 3, 1, 0, 0, 0, 0, 4, 8728);

  // host precompute: per-layer, per-XCD slot bases for the balanced group mapping
  int gid = 0;
  for (int x = 0; x < 8; ++x) h.sb[x] = 0;
  for (int li = 0; li < 6; ++li) {
    int nbx = (h.L[li].M + 127) / 128;
    h.nbyA[li] = (h.L[li].Co + 127) / 128;
    h.g0[li] = gid & 7;
    for (int x = 0; x < 8; ++x) {
      int f = ((x - gid) % 8 + 8) % 8;                  // first group offset on XCD x
      int cnt = (f < nbx) ? (nbx - f + 7) / 8 : 0;      // groups of this layer on XCD x
      h.sb[(li + 1) * 8 + x] = h.sb[li * 8 + x] + h.nbyA[li] * cnt;
    }
    gid += nbx;
  }
  int maxSlots = 0;
  for (int x = 0; x < 8; ++x) if (h.sb[48 + x] > maxSlots) maxSlots = h.sb[48 + x];
  head_grouped<<<dim3(8 * maxSlots), 512, 0, stream>>>(h);
}

// Round 15
// 356.712 us; speedup vs baseline: 1.2226x; 1.2226x over previous
//
#include <hip/hip_runtime.h>
#include <hip/hip_bf16.h>

typedef __attribute__((ext_vector_type(8))) short short8;
typedef __attribute__((ext_vector_type(4))) float f32x4;

__device__ __forceinline__ short f2bf(float f) {
  unsigned u = __float_as_uint(f);
  u += 0x7fffu + ((u >> 16) & 1u);   // RNE
  return (short)(u >> 16);
}

__device__ __forceinline__ void gload16(const short* g, short* l) {
  __builtin_amdgcn_global_load_lds(
      (const __attribute__((address_space(1))) unsigned int*)g,
      (__attribute__((address_space(3))) unsigned int*)l, 16, 0, 0);
}

// ---------------- weight repack segment table ----------------------------------------
struct WSeg { const float* src; short* dst; int Ci; int S; int elems; };
struct WPrep { WSeg seg[20]; };

// ---------------- fused prep kernel ---------------------------------------------------
// One launch, three independent jobs selected by block range:
//   [0, nF0):        feat0 L2Norm + NCHW->padded-NHWC bf16 (46 p-tiles x 16 n)
//   [nF0, nF0+nF1):  feat1 NCHW->padded-NHWC bf16 (12 p x 32 c x 16 n)
//   rest:            weight repack (Co,Ci,S) fp32 -> [co][s][ci] bf16
struct PrepPack {
  const float* f0; short* f0dst; const float* l2w;
  const float* f1; short* f1dst;
  WPrep wp; int wtotal;
  int nF0, nF1;
};

__global__ __launch_bounds__(256) void prep_kernel(PrepPack pp) {
  __shared__ float red[8][32];
  __shared__ float sscale[32];
  __shared__ float tile[32][33];
  int id = blockIdx.x;
  if (id < pp.nF0) {
    // ---- feat0: L2Norm + transpose (H=W=38, Wp=40, nstride=1600, hh=1, C=512) ----
    constexpr int C = 512, H = 38, W = 38, Wp = 40, nstride = 1600, hh = 1;
    int bx = id % 46, n = id / 46;
    int P = H * W;
    int p0 = bx * 32;
    int pl = threadIdx.x & 31, cg = threadIdx.x >> 5;
    const float* s = pp.f0 + (size_t)n * C * P;
    float ss = 0.f;
    int p = p0 + pl;
    if (p < P) {
      for (int k = 0; k < 64; ++k) {
        float v = s[(size_t)(cg * 64 + k) * P + p];
        ss += v * v;
      }
    }
    red[cg][pl] = ss;
    __syncthreads();
    if (threadIdx.x < 32) {
      float tot = 0.f;
      #pragma unroll
      for (int g = 0; g < 8; ++g) tot += red[g][threadIdx.x];
      sscale[threadIdx.x] = 1.0f / (sqrtf(tot) + 1e-10f);
    }
    __syncthreads();
    for (int ct = 0; ct < 16; ++ct) {
      int c0 = ct * 32;
      __syncthreads();
      #pragma unroll
      for (int i = 0; i < 4; ++i) {
        int cl = cg + i * 8;
        tile[cl][pl] = (p < P) ? s[(size_t)(c0 + cl) * P + p] : 0.f;
      }
      __syncthreads();
      #pragma unroll
      for (int i = 0; i < 4; ++i) {
        int pll = cg + i * 8;
        int pp2 = p0 + pll;
        if (pp2 >= P) continue;
        int c = c0 + pl;
        float v = tile[pl][pll] * pp.l2w[c] * sscale[pll];
        int y = pp2 / W, x = pp2 - y * W;
        pp.f0dst[((size_t)n * nstride + (y + hh) * Wp + (x + hh)) * C + c] = f2bf(v);
      }
    }
    return;
  }
  id -= pp.nF0;
  if (id < pp.nF1) {
    // ---- feat1: transpose (C=1024, H=W=19, Wp=21, nstride=441, hh=1) ----
    constexpr int C = 1024, H = 19, W = 19, Wp = 21, nstride = 441, hh = 1;
    int bx = id % 12, byc = (id / 12) % 32, n = id / (12 * 32);
    int P = H * W;
    int p0 = bx * 32, c0 = byc * 32;
    int tp = threadIdx.x & 31, tr = threadIdx.x >> 5;
    const float* s = pp.f1 + (size_t)n * C * P;
    #pragma unroll
    for (int i = 0; i < 4; ++i) {
      int cl = tr + i * 8;
      int p = p0 + tp;
      tile[cl][tp] = (p < P) ? s[(size_t)(c0 + cl) * P + p] : 0.f;
    }
    __syncthreads();
    #pragma unroll
    for (int i = 0; i < 4; ++i) {
      int pl = tr + i * 8;
      int p = p0 + pl;
      if (p >= P) continue;
      int c = c0 + tp;
      float v = tile[tp][pl];
      int y = p / W, x = p - y * W;
      pp.f1dst[((size_t)n * nstride + (y + hh) * Wp + (x + hh)) * C + c] = f2bf(v);
    }
    return;
  }
  id -= pp.nF1;
  // ---- weight repack ----
  int i = id * 256 + threadIdx.x;
  if (i >= pp.wtotal) return;
  int local = i;
  int si = 0;
  while (local >= pp.wp.seg[si].elems) { local -= pp.wp.seg[si].elems; ++si; }
  WSeg sg = pp.wp.seg[si];
  int ci = local % sg.Ci;
  int q  = local / sg.Ci;
  int s  = q % sg.S;
  int co = q / sg.S;
  float v = sg.src[((size_t)co * sg.Ci + ci) * sg.S + s];
  sg.dst[local] = f2bf(v);
}

// ---------------- conv params --------------------------------------------------------
struct ConvP {
  const short* in;   // bf16 padded NHWC [16][iHp][iWp][Ci]
  const short* w;    // bf16 [Co][S][Ci]
  const float* b1;   // bias (extra) / cls bias (head)
  const float* b2;   // box bias (head)
  short* out_bf;     // extra: padded bf16 NHWC out
  float* out_f;      // head: packed d_out
  int M, Ci, iHp, iWp, Ho, Wo, Co;
  int S, kdim, stride, ioff;
  int oWp, onstride, oh;
  int mbox, row_base;
};

// --- BK/wave-parameterized 2-buffer, 1-barrier/K-step implicit-GEMM core + swizzle ---
// Per K-step: stage(k+1) into buf^1 -> ds_read buf -> KK x AM x AN MFMA ->
// __syncthreads (vmcnt0 drain = RAW for k+1, WAR for buf). Heads: 8 waves (2Mx4N,
// 512 thr), 128x128/BK=64, 64KB LDS -> 2 blocks/CU = 16 waves/CU. Extras: 4 waves,
// 64x64/BK=128. Regression ledger: hand-vmcnt (r4/r5), unbalanced XCD-chunk swizzle
// (r6), persistent grid-sync overlap (r11), work-stealing overlap (r12), single-block
// tail fusion (r14) — all tested, all slower. This structure is the verified optimum.
// Swizzle (rule #21 both-sides): stage global chunk (t&(CPR-1))^(sr&(CPR-1)) to linear
// LDS; read chunk ((kk<<2)|kgrp)^(r&(CPR-1)) — same involution, bank-uniform b128.
template<int BM, int BN, int BK, int WM, int WN, bool HEAD>
__device__ __forceinline__ void conv_core(const ConvP p, int bx, int by) {
  constexpr int NT  = WM * WN * 64;
  constexpr int CPR = BK / 8;
  constexpr int RPP = NT / CPR;
  constexpr int NRA = BM / RPP, NRB = BN / RPP;
  constexpr int AM = BM / WM / 16, AN = BN / WN / 16, KK = BK / 32;
  constexpr int ABUF = BM * BK, BBUF = BN * BK;
  __shared__ short As[2 * ABUF];
  __shared__ short Bs[2 * BBUF];
  const int t = threadIdx.x, lane = t & 63, wave = t >> 6;
  const int HW = p.Ho * p.Wo;
  const int sr = t / CPR;
  const int slot = ((t & (CPR - 1)) ^ (sr & (CPR - 1))) * 8;

  const short* aBase[NRA];
  const short* bBase[NRB];
  #pragma unroll
  for (int i = 0; i < NRA; ++i) {
    int pos = bx * BM + sr + i * RPP; if (pos >= p.M) pos = p.M - 1;
    int n = pos / HW, rem = pos - n * HW;
    int yo = rem / p.Wo, xo = rem - yo * p.Wo;
    aBase[i] = p.in + ((size_t)(n * p.iHp + yo * p.stride + p.ioff) * p.iWp
                      + xo * p.stride + p.ioff) * p.Ci + slot;
  }
  #pragma unroll
  for (int i = 0; i < NRB; ++i) {
    int co = by * BN + sr + i * RPP; if (co >= p.Co) co = p.Co - 1;
    bBase[i] = p.w + (size_t)co * p.S * p.Ci + slot;
  }
  const int cs = p.Ci / BK;
  const int total = p.S * cs;

  auto stage = [&](int buf, int aoff, int boff) {
    #pragma unroll
    for (int i = 0; i < NRA; ++i)
      gload16(aBase[i] + aoff, &As[buf * ABUF + i * (NT * 8) + t * 8]);
    #pragma unroll
    for (int i = 0; i < NRB; ++i)
      gload16(bBase[i] + boff, &Bs[buf * BBUF + i * (NT * 8) + t * 8]);
  };

  int ntap = 0, ncc = 0;
  auto aoff_cur = [&]() -> int {
    if (p.S == 1) return ncc * BK;
    unsigned dy = (unsigned)ntap / 3u;
    int dx = ntap - (int)dy * 3;
    return ((int)dy * p.iWp + dx) * p.Ci + ncc * BK;
  };

  stage(0, aoff_cur(), 0);
  ++ncc; if (ncc == cs) { ncc = 0; ++ntap; }
  __syncthreads();                       // tile 0 landed

  f32x4 acc[AM][AN];
  #pragma unroll
  for (int i = 0; i < AM; ++i)
    #pragma unroll
    for (int j = 0; j < AN; ++j)
      acc[i][j] = (f32x4){0.f, 0.f, 0.f, 0.f};

  const int wr = (wave / WN) * (BM / WM), wc = (wave % WN) * (BN / WN);
  const int lrow = lane & 15, kgrp = lane >> 4;

  int cur = 0;
  for (int ks = 0; ks < total; ++ks) {
    if (ks + 1 < total) {                // issue next tile's loads FIRST (overlap)
      stage(cur ^ 1, aoff_cur(), (ks + 1) * BK);
      ++ncc; if (ncc == cs) { ncc = 0; ++ntap; }
    }
    const short* aRd0 = &As[cur * ABUF];
    const short* bRd0 = &Bs[cur * BBUF];
    short8 a[AM][KK], b[AN][KK];
    #pragma unroll
    for (int i = 0; i < AM; ++i) {
      int r = wr + i * 16 + lrow;
      #pragma unroll
      for (int kk = 0; kk < KK; ++kk) {
        int ch = ((kk << 2) | kgrp) ^ (r & (CPR - 1));
        a[i][kk] = *reinterpret_cast<const short8*>(aRd0 + r * BK + ch * 8);
      }
    }
    #pragma unroll
    for (int j = 0; j < AN; ++j) {
      int r = wc + j * 16 + lrow;
      #pragma unroll
      for (int kk = 0; kk < KK; ++kk) {
        int ch = ((kk << 2) | kgrp) ^ (r & (CPR - 1));
        b[j][kk] = *reinterpret_cast<const short8*>(bRd0 + r * BK + ch * 8);
      }
    }
    #pragma unroll
    for (int kk = 0; kk < KK; ++kk)
      #pragma unroll
      for (int i = 0; i < AM; ++i)
        #pragma unroll
        for (int j = 0; j < AN; ++j)
          acc[i][j] = __builtin_amdgcn_mfma_f32_16x16x32_bf16(a[i][kk], b[j][kk], acc[i][j], 0, 0, 0);
    __syncthreads();                     // drains vmcnt(0): next tile ready; reads done
    cur ^= 1;
  }

  const int mk = p.mbox * 81;
  const int rb_ = (lane >> 4) * 4, cl_ = lane & 15;
  #pragma unroll
  for (int i = 0; i < AM; ++i)
    #pragma unroll
    for (int j = 0; j < AN; ++j)
      #pragma unroll
      for (int q = 0; q < 4; ++q) {
        int po = bx * BM + wr + i * 16 + rb_ + q;
        int co = by * BN + wc + j * 16 + cl_;
        if (po >= p.M || co >= p.Co) continue;
        float v = acc[i][j][q];
        if (!HEAD) {
          int n2 = po / HW, sp = po - n2 * HW;
          int y = sp / p.Wo, x = sp - y * p.Wo;
          float v2 = fmaxf(v + p.b1[co], 0.f);
          p.out_bf[((size_t)n2 * p.onstride + (y + p.oh) * p.oWp + (x + p.oh)) * p.Co + co] = f2bf(v2);
        } else {
          int n2 = po / HW, sp = po - n2 * HW;
          int mi, col; float bias;
          if (co < mk) { mi = co / 81; col = co - mi * 81; bias = p.b1[co]; }
          else { int cbx = co - mk; mi = cbx >> 2; col = 81 + (cbx & 3); bias = p.b2[cbx]; }
          size_t orow = (size_t)n2 * 8732 + p.row_base + (size_t)sp * p.mbox + mi;
          p.out_f[orow * 85 + col] = v + bias;
        }
      }
}

__global__ __launch_bounds__(256) void conv_tile64(ConvP p) {
  conv_core<64, 64, 128, 2, 2, false>(p, blockIdx.x, blockIdx.y);
}

// ------ grouped head kernel: group-preserving, round-robin-balanced XCD mapping ------
// Reuse unit = group (layer, bx) with nby member blocks sharing one A-panel. Hardware
// maps physical block p -> XCD p&7. Groups assigned round-robin (gid%8 -> XCD) so each
// XCD gets a proportional mix of long-K and short-K groups; a group's members occupy
// consecutive slots of ONE XCD. sb[li*8+x] = first slot of layer li on XCD x.
struct HeadPack { ConvP L[6]; int g0[6]; int nbyA[6]; int sb[56]; };

__global__ __launch_bounds__(512) void head_grouped(HeadPack h) {
  int p = blockIdx.x, x = p & 7, s = p >> 3;
  if (s >= h.sb[48 + x]) return;         // padding block
  int li = 0;
  #pragma unroll
  for (int i = 1; i < 6; ++i) if (s >= h.sb[i * 8 + x]) li = i;
  int r = s - h.sb[li * 8 + x];
  int nby = h.nbyA[li];
  int k = r / nby, by = r - k * nby;
  int bx = ((x - h.g0[li]) & 7) + 8 * k; // bx of the k-th group of layer li on XCD x
  conv_core<128, 128, 64, 2, 4, true>(h.L[li], bx, by);
}

extern "C" void kernel_launch(void* const* d_in, const int* in_sizes, int n_in,
                              void* d_out, int out_size, void* d_ws, size_t ws_size,
                              hipStream_t stream) {
  const float* feat0 = (const float*)d_in[0];
  const float* feat1 = (const float*)d_in[1];
  const float* l2w   = (const float*)d_in[2];
  const float* ew[8]; const float* eb[8];
  for (int i = 0; i < 8; ++i) { ew[i] = (const float*)d_in[3 + 2 * i]; eb[i] = (const float*)d_in[4 + 2 * i]; }
  const float* cw[6]; const float* cb[6]; const float* bw[6]; const float* bb[6];
  for (int i = 0; i < 6; ++i) {
    cw[i] = (const float*)d_in[19 + 4 * i]; cb[i] = (const float*)d_in[20 + 4 * i];
    bw[i] = (const float*)d_in[21 + 4 * i]; bb[i] = (const float*)d_in[22 + 4 * i];
  }
  float* out = (float*)d_out;
  char* ws = (char*)d_ws;
  size_t off = 0;
  auto alloc = [&](size_t bytes) -> char* {
    char* p = ws + off;
    off = (off + bytes + 255) & ~(size_t)255;
    return p;
  };
  char* featStart = ws + off;
  short* f0b = (short*)alloc((size_t)16 * 40 * 40 * 512 * 2);   // 38x38, h=1
  short* f1b = (short*)alloc((size_t)16 * 21 * 21 * 1024 * 2);  // 19x19, h=1
  short* xe0 = (short*)alloc((size_t)16 * 21 * 21 * 256 * 2);   // 19x19, h=1
  short* f2b = (short*)alloc((size_t)16 * 12 * 12 * 512 * 2);   // 10x10, h=1
  short* xe2 = (short*)alloc((size_t)16 * 12 * 12 * 128 * 2);   // 10x10, h=1
  short* f3b = (short*)alloc((size_t)16 * 7 * 7 * 256 * 2);     // 5x5,  h=1
  short* xe4 = (short*)alloc((size_t)16 * 5 * 5 * 128 * 2);     // 5x5,  h=0
  short* f4b = (short*)alloc((size_t)16 * 5 * 5 * 256 * 2);     // 3x3,  h=1
  short* xe6 = (short*)alloc((size_t)16 * 3 * 3 * 128 * 2);     // 3x3,  h=0
  short* f5b = (short*)alloc((size_t)16 * 3 * 3 * 256 * 2);     // 1x1,  h=1
  size_t featBytes = (size_t)((ws + off) - featStart);

  static const int eCo[8] = {256, 512, 128, 256, 128, 256, 128, 256};
  static const int eCi[8] = {1024, 256, 512, 128, 256, 128, 256, 128};
  static const int eS[8]  = {1, 9, 1, 9, 1, 9, 1, 9};
  static const int mbox[6] = {4, 6, 6, 6, 4, 4};
  static const int hCi[6] = {512, 1024, 512, 256, 256, 256};

  WPrep wp; int total = 0; int segi = 0;
  short* ewb[8]; short* hwb[6];
  for (int i = 0; i < 8; ++i) {
    int e = eCo[i] * eCi[i] * eS[i];
    ewb[i] = (short*)alloc((size_t)e * 2);
    wp.seg[segi++] = {ew[i], ewb[i], eCi[i], eS[i], e};
    total += e;
  }
  for (int L = 0; L < 6; ++L) {
    int co = mbox[L] * 85;
    int e = co * hCi[L] * 9;
    hwb[L] = (short*)alloc((size_t)e * 2);
    int ecls = mbox[L] * 81 * hCi[L] * 9;
    wp.seg[segi++] = {cw[L], hwb[L], hCi[L], 9, ecls};
    wp.seg[segi++] = {bw[L], hwb[L] + (size_t)mbox[L] * 81 * 9 * hCi[L], hCi[L], 9, e - ecls};
    total += e;
  }

  hipMemsetAsync(featStart, 0, featBytes, stream);

  // fused prep: feat0(L2Norm+transpose) + feat1(transpose) + weight repack, 1 launch
  PrepPack pp;
  pp.f0 = feat0; pp.f0dst = f0b; pp.l2w = l2w;
  pp.f1 = feat1; pp.f1dst = f1b;
  pp.wp = wp; pp.wtotal = total;
  pp.nF0 = 46 * 16;
  pp.nF1 = 12 * 32 * 16;
  int nPrep = pp.nF0 + pp.nF1 + (total + 255) / 256;
  prep_kernel<<<dim3(nPrep), 256, 0, stream>>>(pp);

  auto mkP = [&](const short* in, const short* wbuf, const float* b1, const float* b2,
                 short* outb, float* outf, int Ci, int iHp, int iWp, int Ho, int Wo,
                 int Co, int S, int kd, int st, int ioff, int oWp, int onstride, int oh,
                 int m, int rb) {
    ConvP p{}; p.in = in; p.w = wbuf; p.b1 = b1; p.b2 = b2; p.out_bf = outb; p.out_f = outf;
    p.M = 16 * Ho * Wo; p.Ci = Ci; p.iHp = iHp; p.iWp = iWp; p.Ho = Ho; p.Wo = Wo; p.Co = Co;
    p.S = S; p.kdim = kd; p.stride = st; p.ioff = ioff;
    p.oWp = oWp; p.onstride = onstride; p.oh = oh; p.mbox = m; p.row_base = rb;
    return p;
  };
  auto run64 = [&](ConvP p) {
    conv_tile64<<<dim3((p.M + 63) / 64, (p.Co + 63) / 64), 256, 0, stream>>>(p);
  };

  // extras chain (BK=128 pipelined 64x64; grids < CU count so occupancy cap moot)
  run64(mkP(f1b, ewb[0], eb[0], nullptr, xe0, nullptr, 1024, 21, 21, 19, 19, 256, 1, 1, 1, 1, 21, 441, 1, 0, 0));
  run64(mkP(xe0, ewb[1], eb[1], nullptr, f2b, nullptr,  256, 21, 21, 10, 10, 512, 9, 3, 2, 0, 12, 144, 1, 0, 0));
  run64(mkP(f2b, ewb[2], eb[2], nullptr, xe2, nullptr,  512, 12, 12, 10, 10, 128, 1, 1, 1, 1, 12, 144, 1, 0, 0));
  run64(mkP(xe2, ewb[3], eb[3], nullptr, f3b, nullptr,  128, 12, 12,  5,  5, 256, 9, 3, 2, 0,  7,  49, 1, 0, 0));
  run64(mkP(f3b, ewb[4], eb[4], nullptr, xe4, nullptr,  256,  7,  7,  5,  5, 128, 1, 1, 1, 1,  5,  25, 0, 0, 0));
  run64(mkP(xe4, ewb[5], eb[5], nullptr, f4b, nullptr,  128,  5,  5,  3,  3, 256, 9, 3, 1, 0,  5,  25, 1, 0, 0));
  run64(mkP(f4b, ewb[6], eb[6], nullptr, xe6, nullptr,  256,  5,  5,  3,  3, 128, 1, 1, 1, 1,  3,   9, 0, 0, 0));
  run64(mkP(xe6, ewb[7], eb[7], nullptr, f5b, nullptr,  128,  3,  3,  1,  1, 256, 9, 3, 1, 0,  3,   9, 1, 0, 0));

  // all 6 heads in ONE launch (long-K head1 first in group enumeration)
  HeadPack h;
  h.L[0] = mkP(f1b, hwb[1], cb[1], bb[1], nullptr, out, 1024, 21, 21, 19, 19, 6 * 85, 9, 3, 1, 0, 0, 0, 0, 6, 5776);
  h.L[1] = mkP(f0b, hwb[0], cb[0], bb[0], nullptr, out,  512, 40, 40, 38, 38, 4 * 85, 9, 3, 1, 0, 0, 0, 0, 4, 0);
  h.L[2] = mkP(f2b, hwb[2], cb[2], bb[2], nullptr, out,  512, 12, 12, 10, 10, 6 * 85, 9, 3, 1, 0, 0, 0, 0, 6, 7942);
  h.L[3] = mkP(f3b, hwb[3], cb[3], bb[3], nullptr, out,  256,  7,  7,  5,  5, 6 * 85, 9, 3, 1, 0, 0, 0, 0, 6, 8542);
  h.L[4] = mkP(f4b, hwb[4], cb[4], bb[4], nullptr, out,  256,  5,  5,  3,  3, 4 * 85, 9, 3, 1, 0, 0, 0, 0, 4, 8692);
  h.L[5] = mkP(f5b, hwb[5], cb[5], bb[5], nullptr, out,  256,  3,  3,  1,  1, 4 * 85, 9, 3, 1, 0, 0, 0, 0, 4, 8728);

  // host precompute: per-layer, per-XCD slot bases for the balanced group mapping
  int gid = 0;
  for (int x = 0; x < 8; ++x) h.sb[x] = 0;
  for (int li = 0; li < 6; ++li) {
    int nbx = (h.L[li].M + 127) / 128;
    h.nbyA[li] = (h.L[li].Co + 127) / 128;
    h.g0[li] = gid & 7;
    for (int x = 0; x < 8; ++x) {
      int f = ((x - gid) % 8 + 8) % 8;                  // first group offset on XCD x
      int cnt = (f < nbx) ? (nbx - f + 7) / 8 : 0;      // groups of this layer on XCD x
      h.sb[(li + 1) * 8 + x] = h.sb[li * 8 + x] + h.nbyA[li] * cnt;
    }
    gid += nbx;
  }
  int maxSlots = 0;
  for (int x = 0; x < 8; ++x) if (h.sb[48 + x] > maxSlots) maxSlots = h.sb[48 + x];
  head_grouped<<<dim3(8 * maxSlots), 512, 0, stream>>>(h);
}

// Round 16
// 341.339 us; speedup vs baseline: 1.2776x; 1.0450x over previous
//
#include <hip/hip_runtime.h>
#include <hip/hip_bf16.h>

typedef __attribute__((ext_vector_type(8))) short short8;
typedef __attribute__((ext_vector_type(4))) float f32x4;

__device__ __forceinline__ short f2bf(float f) {
  unsigned u = __float_as_uint(f);
  u += 0x7fffu + ((u >> 16) & 1u);   // RNE
  return (short)(u >> 16);
}

__device__ __forceinline__ void gload16(const short* g, short* l) {
  __builtin_amdgcn_global_load_lds(
      (const __attribute__((address_space(1))) unsigned int*)g,
      (__attribute__((address_space(3))) unsigned int*)l, 16, 0, 0);
}

// ---------------- weight repack segment table ----------------------------------------
struct WSeg { const float* src; short* dst; int Ci; int S; int elems; };
struct WPrep { WSeg seg[20]; };

// ---------------- fused prep kernel ---------------------------------------------------
// One launch, three independent jobs selected by block range:
//   [0, nF0):        feat0 L2Norm + NCHW->padded-NHWC bf16 (46 p-tiles x 16 n)
//   [nF0, nF0+nF1):  feat1 NCHW->padded-NHWC bf16 (12 p x 32 c x 16 n)
//   rest:            weight repack (Co,Ci,S) fp32 -> [co][s][ci] bf16
struct PrepPack {
  const float* f0; short* f0dst; const float* l2w;
  const float* f1; short* f1dst;
  WPrep wp; int wtotal;
  int nF0, nF1;
};

__global__ __launch_bounds__(256) void prep_kernel(PrepPack pp) {
  __shared__ float red[8][32];
  __shared__ float sscale[32];
  __shared__ float tile[32][33];
  int id = blockIdx.x;
  if (id < pp.nF0) {
    // ---- feat0: L2Norm + transpose (H=W=38, Wp=40, nstride=1600, hh=1, C=512) ----
    constexpr int C = 512, H = 38, W = 38, Wp = 40, nstride = 1600, hh = 1;
    int bx = id % 46, n = id / 46;
    int P = H * W;
    int p0 = bx * 32;
    int pl = threadIdx.x & 31, cg = threadIdx.x >> 5;
    const float* s = pp.f0 + (size_t)n * C * P;
    float ss = 0.f;
    int p = p0 + pl;
    if (p < P) {
      for (int k = 0; k < 64; ++k) {
        float v = s[(size_t)(cg * 64 + k) * P + p];
        ss += v * v;
      }
    }
    red[cg][pl] = ss;
    __syncthreads();
    if (threadIdx.x < 32) {
      float tot = 0.f;
      #pragma unroll
      for (int g = 0; g < 8; ++g) tot += red[g][threadIdx.x];
      sscale[threadIdx.x] = 1.0f / (sqrtf(tot) + 1e-10f);
    }
    __syncthreads();
    for (int ct = 0; ct < 16; ++ct) {
      int c0 = ct * 32;
      __syncthreads();
      #pragma unroll
      for (int i = 0; i < 4; ++i) {
        int cl = cg + i * 8;
        tile[cl][pl] = (p < P) ? s[(size_t)(c0 + cl) * P + p] : 0.f;
      }
      __syncthreads();
      #pragma unroll
      for (int i = 0; i < 4; ++i) {
        int pll = cg + i * 8;
        int pp2 = p0 + pll;
        if (pp2 >= P) continue;
        int c = c0 + pl;
        float v = tile[pl][pll] * pp.l2w[c] * sscale[pll];
        int y = pp2 / W, x = pp2 - y * W;
        pp.f0dst[((size_t)n * nstride + (y + hh) * Wp + (x + hh)) * C + c] = f2bf(v);
      }
    }
    return;
  }
  id -= pp.nF0;
  if (id < pp.nF1) {
    // ---- feat1: transpose (C=1024, H=W=19, Wp=21, nstride=441, hh=1) ----
    constexpr int C = 1024, H = 19, W = 19, Wp = 21, nstride = 441, hh = 1;
    int bx = id % 12, byc = (id / 12) % 32, n = id / (12 * 32);
    int P = H * W;
    int p0 = bx * 32, c0 = byc * 32;
    int tp = threadIdx.x & 31, tr = threadIdx.x >> 5;
    const float* s = pp.f1 + (size_t)n * C * P;
    #pragma unroll
    for (int i = 0; i < 4; ++i) {
      int cl = tr + i * 8;
      int p = p0 + tp;
      tile[cl][tp] = (p < P) ? s[(size_t)(c0 + cl) * P + p] : 0.f;
    }
    __syncthreads();
    #pragma unroll
    for (int i = 0; i < 4; ++i) {
      int pl = tr + i * 8;
      int p = p0 + pl;
      if (p >= P) continue;
      int c = c0 + tp;
      float v = tile[tp][pl];
      int y = p / W, x = p - y * W;
      pp.f1dst[((size_t)n * nstride + (y + hh) * Wp + (x + hh)) * C + c] = f2bf(v);
    }
    return;
  }
  id -= pp.nF1;
  // ---- weight repack ----
  int i = id * 256 + threadIdx.x;
  if (i >= pp.wtotal) return;
  int local = i;
  int si = 0;
  while (local >= pp.wp.seg[si].elems) { local -= pp.wp.seg[si].elems; ++si; }
  WSeg sg = pp.wp.seg[si];
  int ci = local % sg.Ci;
  int q  = local / sg.Ci;
  int s  = q % sg.S;
  int co = q / sg.S;
  float v = sg.src[((size_t)co * sg.Ci + ci) * sg.S + s];
  sg.dst[local] = f2bf(v);
}

// ---------------- conv params --------------------------------------------------------
struct ConvP {
  const short* in;   // bf16 padded NHWC [16][iHp][iWp][Ci]
  const short* w;    // bf16 [Co][S][Ci]
  const float* b1;   // bias (extra) / cls bias (head)
  const float* b2;   // box bias (head)
  short* out_bf;     // extra: padded bf16 NHWC out
  float* out_f;      // head: packed d_out
  int M, Ci, iHp, iWp, Ho, Wo, Co;
  int S, kdim, stride, ioff;
  int oWp, onstride, oh;
  int mbox, row_base;
};

// --- BK/wave-parameterized 2-buffer, 1-barrier/K-step implicit-GEMM core + swizzle ---
// Per K-step: stage(k+1) into buf^1 -> ds_read buf -> KK x AM x AN MFMA ->
// __syncthreads (vmcnt0 drain = RAW for k+1, WAR for buf). Heads: 8 waves (2Mx4N,
// 512 thr), 128x128/BK=64, 64KB LDS -> 2 blocks/CU = 16 waves/CU. Extras: 8 waves
// (r16: was 4 — TLP doubling, same lever as r10's head win), 64x64/BK=128.
// Regression ledger: hand-vmcnt (r4/r5), unbalanced XCD-chunk swizzle (r6), persistent
// grid-sync overlap (r11), work-stealing overlap (r12), single-block tail fusion (r14),
// 256²/8-phase heads (checked: 46-182 blocks, structurally underfilled) — all dead ends.
// Swizzle (rule #21 both-sides): stage global chunk (t&(CPR-1))^(sr&(CPR-1)) to linear
// LDS; read chunk ((kk<<2)|kgrp)^(r&(CPR-1)) — same involution, bank-uniform b128.
template<int BM, int BN, int BK, int WM, int WN, bool HEAD>
__device__ __forceinline__ void conv_core(const ConvP p, int bx, int by) {
  constexpr int NT  = WM * WN * 64;
  constexpr int CPR = BK / 8;
  constexpr int RPP = NT / CPR;
  constexpr int NRA = BM / RPP, NRB = BN / RPP;
  constexpr int AM = BM / WM / 16, AN = BN / WN / 16, KK = BK / 32;
  constexpr int ABUF = BM * BK, BBUF = BN * BK;
  __shared__ short As[2 * ABUF];
  __shared__ short Bs[2 * BBUF];
  const int t = threadIdx.x, lane = t & 63, wave = t >> 6;
  const int HW = p.Ho * p.Wo;
  const int sr = t / CPR;
  const int slot = ((t & (CPR - 1)) ^ (sr & (CPR - 1))) * 8;

  const short* aBase[NRA];
  const short* bBase[NRB];
  #pragma unroll
  for (int i = 0; i < NRA; ++i) {
    int pos = bx * BM + sr + i * RPP; if (pos >= p.M) pos = p.M - 1;
    int n = pos / HW, rem = pos - n * HW;
    int yo = rem / p.Wo, xo = rem - yo * p.Wo;
    aBase[i] = p.in + ((size_t)(n * p.iHp + yo * p.stride + p.ioff) * p.iWp
                      + xo * p.stride + p.ioff) * p.Ci + slot;
  }
  #pragma unroll
  for (int i = 0; i < NRB; ++i) {
    int co = by * BN + sr + i * RPP; if (co >= p.Co) co = p.Co - 1;
    bBase[i] = p.w + (size_t)co * p.S * p.Ci + slot;
  }
  const int cs = p.Ci / BK;
  const int total = p.S * cs;

  auto stage = [&](int buf, int aoff, int boff) {
    #pragma unroll
    for (int i = 0; i < NRA; ++i)
      gload16(aBase[i] + aoff, &As[buf * ABUF + i * (NT * 8) + t * 8]);
    #pragma unroll
    for (int i = 0; i < NRB; ++i)
      gload16(bBase[i] + boff, &Bs[buf * BBUF + i * (NT * 8) + t * 8]);
  };

  int ntap = 0, ncc = 0;
  auto aoff_cur = [&]() -> int {
    if (p.S == 1) return ncc * BK;
    unsigned dy = (unsigned)ntap / 3u;
    int dx = ntap - (int)dy * 3;
    return ((int)dy * p.iWp + dx) * p.Ci + ncc * BK;
  };

  stage(0, aoff_cur(), 0);
  ++ncc; if (ncc == cs) { ncc = 0; ++ntap; }
  __syncthreads();                       // tile 0 landed

  f32x4 acc[AM][AN];
  #pragma unroll
  for (int i = 0; i < AM; ++i)
    #pragma unroll
    for (int j = 0; j < AN; ++j)
      acc[i][j] = (f32x4){0.f, 0.f, 0.f, 0.f};

  const int wr = (wave / WN) * (BM / WM), wc = (wave % WN) * (BN / WN);
  const int lrow = lane & 15, kgrp = lane >> 4;

  int cur = 0;
  for (int ks = 0; ks < total; ++ks) {
    if (ks + 1 < total) {                // issue next tile's loads FIRST (overlap)
      stage(cur ^ 1, aoff_cur(), (ks + 1) * BK);
      ++ncc; if (ncc == cs) { ncc = 0; ++ntap; }
    }
    const short* aRd0 = &As[cur * ABUF];
    const short* bRd0 = &Bs[cur * BBUF];
    short8 a[AM][KK], b[AN][KK];
    #pragma unroll
    for (int i = 0; i < AM; ++i) {
      int r = wr + i * 16 + lrow;
      #pragma unroll
      for (int kk = 0; kk < KK; ++kk) {
        int ch = ((kk << 2) | kgrp) ^ (r & (CPR - 1));
        a[i][kk] = *reinterpret_cast<const short8*>(aRd0 + r * BK + ch * 8);
      }
    }
    #pragma unroll
    for (int j = 0; j < AN; ++j) {
      int r = wc + j * 16 + lrow;
      #pragma unroll
      for (int kk = 0; kk < KK; ++kk) {
        int ch = ((kk << 2) | kgrp) ^ (r & (CPR - 1));
        b[j][kk] = *reinterpret_cast<const short8*>(bRd0 + r * BK + ch * 8);
      }
    }
    #pragma unroll
    for (int kk = 0; kk < KK; ++kk)
      #pragma unroll
      for (int i = 0; i < AM; ++i)
        #pragma unroll
        for (int j = 0; j < AN; ++j)
          acc[i][j] = __builtin_amdgcn_mfma_f32_16x16x32_bf16(a[i][kk], b[j][kk], acc[i][j], 0, 0, 0);
    __syncthreads();                     // drains vmcnt(0): next tile ready; reads done
    cur ^= 1;
  }

  const int mk = p.mbox * 81;
  const int rb_ = (lane >> 4) * 4, cl_ = lane & 15;
  #pragma unroll
  for (int i = 0; i < AM; ++i)
    #pragma unroll
    for (int j = 0; j < AN; ++j)
      #pragma unroll
      for (int q = 0; q < 4; ++q) {
        int po = bx * BM + wr + i * 16 + rb_ + q;
        int co = by * BN + wc + j * 16 + cl_;
        if (po >= p.M || co >= p.Co) continue;
        float v = acc[i][j][q];
        if (!HEAD) {
          int n2 = po / HW, sp = po - n2 * HW;
          int y = sp / p.Wo, x = sp - y * p.Wo;
          float v2 = fmaxf(v + p.b1[co], 0.f);
          p.out_bf[((size_t)n2 * p.onstride + (y + p.oh) * p.oWp + (x + p.oh)) * p.Co + co] = f2bf(v2);
        } else {
          int n2 = po / HW, sp = po - n2 * HW;
          int mi, col; float bias;
          if (co < mk) { mi = co / 81; col = co - mi * 81; bias = p.b1[co]; }
          else { int cbx = co - mk; mi = cbx >> 2; col = 81 + (cbx & 3); bias = p.b2[cbx]; }
          size_t orow = (size_t)n2 * 8732 + p.row_base + (size_t)sp * p.mbox + mi;
          p.out_f[orow * 85 + col] = v + bias;
        }
      }
}

__global__ __launch_bounds__(512) void conv_tile64(ConvP p) {
  conv_core<64, 64, 128, 2, 4, false>(p, blockIdx.x, blockIdx.y);
}

// ------ grouped head kernel: group-preserving, round-robin-balanced XCD mapping ------
// Reuse unit = group (layer, bx) with nby member blocks sharing one A-panel. Hardware
// maps physical block p -> XCD p&7. Groups assigned round-robin (gid%8 -> XCD) so each
// XCD gets a proportional mix of long-K and short-K groups; a group's members occupy
// consecutive slots of ONE XCD. sb[li*8+x] = first slot of layer li on XCD x.
struct HeadPack { ConvP L[6]; int g0[6]; int nbyA[6]; int sb[56]; };

__global__ __launch_bounds__(512) void head_grouped(HeadPack h) {
  int p = blockIdx.x, x = p & 7, s = p >> 3;
  if (s >= h.sb[48 + x]) return;         // padding block
  int li = 0;
  #pragma unroll
  for (int i = 1; i < 6; ++i) if (s >= h.sb[i * 8 + x]) li = i;
  int r = s - h.sb[li * 8 + x];
  int nby = h.nbyA[li];
  int k = r / nby, by = r - k * nby;
  int bx = ((x - h.g0[li]) & 7) + 8 * k; // bx of the k-th group of layer li on XCD x
  conv_core<128, 128, 64, 2, 4, true>(h.L[li], bx, by);
}

extern "C" void kernel_launch(void* const* d_in, const int* in_sizes, int n_in,
                              void* d_out, int out_size, void* d_ws, size_t ws_size,
                              hipStream_t stream) {
  const float* feat0 = (const float*)d_in[0];
  const float* feat1 = (const float*)d_in[1];
  const float* l2w   = (const float*)d_in[2];
  const float* ew[8]; const float* eb[8];
  for (int i = 0; i < 8; ++i) { ew[i] = (const float*)d_in[3 + 2 * i]; eb[i] = (const float*)d_in[4 + 2 * i]; }
  const float* cw[6]; const float* cb[6]; const float* bw[6]; const float* bb[6];
  for (int i = 0; i < 6; ++i) {
    cw[i] = (const float*)d_in[19 + 4 * i]; cb[i] = (const float*)d_in[20 + 4 * i];
    bw[i] = (const float*)d_in[21 + 4 * i]; bb[i] = (const float*)d_in[22 + 4 * i];
  }
  float* out = (float*)d_out;
  char* ws = (char*)d_ws;
  size_t off = 0;
  auto alloc = [&](size_t bytes) -> char* {
    char* p = ws + off;
    off = (off + bytes + 255) & ~(size_t)255;
    return p;
  };
  char* featStart = ws + off;
  short* f0b = (short*)alloc((size_t)16 * 40 * 40 * 512 * 2);   // 38x38, h=1
  short* f1b = (short*)alloc((size_t)16 * 21 * 21 * 1024 * 2);  // 19x19, h=1
  short* xe0 = (short*)alloc((size_t)16 * 21 * 21 * 256 * 2);   // 19x19, h=1
  short* f2b = (short*)alloc((size_t)16 * 12 * 12 * 512 * 2);   // 10x10, h=1
  short* xe2 = (short*)alloc((size_t)16 * 12 * 12 * 128 * 2);   // 10x10, h=1
  short* f3b = (short*)alloc((size_t)16 * 7 * 7 * 256 * 2);     // 5x5,  h=1
  short* xe4 = (short*)alloc((size_t)16 * 5 * 5 * 128 * 2);     // 5x5,  h=0
  short* f4b = (short*)alloc((size_t)16 * 5 * 5 * 256 * 2);     // 3x3,  h=1
  short* xe6 = (short*)alloc((size_t)16 * 3 * 3 * 128 * 2);     // 3x3,  h=0
  short* f5b = (short*)alloc((size_t)16 * 3 * 3 * 256 * 2);     // 1x1,  h=1
  size_t featBytes = (size_t)((ws + off) - featStart);

  static const int eCo[8] = {256, 512, 128, 256, 128, 256, 128, 256};
  static const int eCi[8] = {1024, 256, 512, 128, 256, 128, 256, 128};
  static const int eS[8]  = {1, 9, 1, 9, 1, 9, 1, 9};
  static const int mbox[6] = {4, 6, 6, 6, 4, 4};
  static const int hCi[6] = {512, 1024, 512, 256, 256, 256};

  WPrep wp; int total = 0; int segi = 0;
  short* ewb[8]; short* hwb[6];
  for (int i = 0; i < 8; ++i) {
    int e = eCo[i] * eCi[i] * eS[i];
    ewb[i] = (short*)alloc((size_t)e * 2);
    wp.seg[segi++] = {ew[i], ewb[i], eCi[i], eS[i], e};
    total += e;
  }
  for (int L = 0; L < 6; ++L) {
    int co = mbox[L] * 85;
    int e = co * hCi[L] * 9;
    hwb[L] = (short*)alloc((size_t)e * 2);
    int ecls = mbox[L] * 81 * hCi[L] * 9;
    wp.seg[segi++] = {cw[L], hwb[L], hCi[L], 9, ecls};
    wp.seg[segi++] = {bw[L], hwb[L] + (size_t)mbox[L] * 81 * 9 * hCi[L], hCi[L], 9, e - ecls};
    total += e;
  }

  hipMemsetAsync(featStart, 0, featBytes, stream);

  // fused prep: feat0(L2Norm+transpose) + feat1(transpose) + weight repack, 1 launch
  PrepPack pp;
  pp.f0 = feat0; pp.f0dst = f0b; pp.l2w = l2w;
  pp.f1 = feat1; pp.f1dst = f1b;
  pp.wp = wp; pp.wtotal = total;
  pp.nF0 = 46 * 16;
  pp.nF1 = 12 * 32 * 16;
  int nPrep = pp.nF0 + pp.nF1 + (total + 255) / 256;
  prep_kernel<<<dim3(nPrep), 256, 0, stream>>>(pp);

  auto mkP = [&](const short* in, const short* wbuf, const float* b1, const float* b2,
                 short* outb, float* outf, int Ci, int iHp, int iWp, int Ho, int Wo,
                 int Co, int S, int kd, int st, int ioff, int oWp, int onstride, int oh,
                 int m, int rb) {
    ConvP p{}; p.in = in; p.w = wbuf; p.b1 = b1; p.b2 = b2; p.out_bf = outb; p.out_f = outf;
    p.M = 16 * Ho * Wo; p.Ci = Ci; p.iHp = iHp; p.iWp = iWp; p.Ho = Ho; p.Wo = Wo; p.Co = Co;
    p.S = S; p.kdim = kd; p.stride = st; p.ioff = ioff;
    p.oWp = oWp; p.onstride = onstride; p.oh = oh; p.mbox = m; p.row_base = rb;
    return p;
  };
  auto run64 = [&](ConvP p) {
    conv_tile64<<<dim3((p.M + 63) / 64, (p.Co + 63) / 64), 512, 0, stream>>>(p);
  };

  // extras chain (BK=128 pipelined 64x64, 8 waves; grids < CU count so LDS cap moot)
  run64(mkP(f1b, ewb[0], eb[0], nullptr, xe0, nullptr, 1024, 21, 21, 19, 19, 256, 1, 1, 1, 1, 21, 441, 1, 0, 0));
  run64(mkP(xe0, ewb[1], eb[1], nullptr, f2b, nullptr,  256, 21, 21, 10, 10, 512, 9, 3, 2, 0, 12, 144, 1, 0, 0));
  run64(mkP(f2b, ewb[2], eb[2], nullptr, xe2, nullptr,  512, 12, 12, 10, 10, 128, 1, 1, 1, 1, 12, 144, 1, 0, 0));
  run64(mkP(xe2, ewb[3], eb[3], nullptr, f3b, nullptr,  128, 12, 12,  5,  5, 256, 9, 3, 2, 0,  7,  49, 1, 0, 0));
  run64(mkP(f3b, ewb[4], eb[4], nullptr, xe4, nullptr,  256,  7,  7,  5,  5, 128, 1, 1, 1, 1,  5,  25, 0, 0, 0));
  run64(mkP(xe4, ewb[5], eb[5], nullptr, f4b, nullptr,  128,  5,  5,  3,  3, 256, 9, 3, 1, 0,  5,  25, 1, 0, 0));
  run64(mkP(f4b, ewb[6], eb[6], nullptr, xe6, nullptr,  256,  5,  5,  3,  3, 128, 1, 1, 1, 1,  3,   9, 0, 0, 0));
  run64(mkP(xe6, ewb[7], eb[7], nullptr, f5b, nullptr,  128,  3,  3,  1,  1, 256, 9, 3, 1, 0,  3,   9, 1, 0, 0));

  // all 6 heads in ONE launch (long-K head1 first in group enumeration)
  HeadPack h;
  h.L[0] = mkP(f1b, hwb[1], cb[1], bb[1], nullptr, out, 1024, 21, 21, 19, 19, 6 * 85, 9, 3, 1, 0, 0, 0, 0, 6, 5776);
  h.L[1] = mkP(f0b, hwb[0], cb[0], bb[0], nullptr, out,  512, 40, 40, 38, 38, 4 * 85, 9, 3, 1, 0, 0, 0, 0, 4, 0);
  h.L[2] = mkP(f2b, hwb[2], cb[2], bb[2], nullptr, out,  512, 12, 12, 10, 10, 6 * 85, 9, 3, 1, 0, 0, 0, 0, 6, 7942);
  h.L[3] = mkP(f3b, hwb[3], cb[3], bb[3], nullptr, out,  256,  7,  7,  5,  5, 6 * 85, 9, 3, 1, 0, 0, 0, 0, 6, 8542);
  h.L[4] = mkP(f4b, hwb[4], cb[4], bb[4], nullptr, out,  256,  5,  5,  3,  3, 4 * 85, 9, 3, 1, 0, 0, 0, 0, 4, 8692);
  h.L[5] = mkP(f5b, hwb[5], cb[5], bb[5], nullptr, out,  256,  3,  3,  1,  1, 4 * 85, 9, 3, 1, 0, 0, 0, 0, 4, 8728);

  // host precompute: per-layer, per-XCD slot bases for the balanced group mapping
  int gid = 0;
  for (int x = 0; x < 8; ++x) h.sb[x] = 0;
  for (int li = 0; li < 6; ++li) {
    int nbx = (h.L[li].M + 127) / 128;
    h.nbyA[li] = (h.L[li].Co + 127) / 128;
    h.g0[li] = gid & 7;
    for (int x = 0; x < 8; ++x) {
      int f = ((x - gid) % 8 + 8) % 8;                  // first group offset on XCD x
      int cnt = (f < nbx) ? (nbx - f + 7) / 8 : 0;      // groups of this layer on XCD x
      h.sb[(li + 1) * 8 + x] = h.sb[li * 8 + x] + h.nbyA[li] * cnt;
    }
    gid += nbx;
  }
  int maxSlots = 0;
  for (int x = 0; x < 8; ++x) if (h.sb[48 + x] > maxSlots) maxSlots = h.sb[48 + x];
  head_grouped<<<dim3(8 * maxSlots), 512, 0, stream>>>(h);
}